// Round 4
// baseline (39.327 us; speedup 1.0000x reference)
//
#include <hip/hip_runtime.h>

#define NN 128
#define HH 256
#define WW 256
#define CC 3
#define HWC (HH * WW * CC)
#define ROWF (WW * CC)       // 768 floats per image row
#define LSF 100              // LDS row stride in floats (25 float4)
#define WIN 100              // window floats per row

__device__ __forceinline__ int reflect_idx(int v, int size) {
    int period = 2 * size - 2;
    int m = v % period;
    if (m < 0) m += period;
    return size - 1 - abs(size - 1 - m);
}

__global__ __launch_bounds__(256) void augment_kernel(
    const float* __restrict__ images,
    const int*   __restrict__ xflip_w,
    const float* __restrict__ xflip_gate,
    const int*   __restrict__ yflip_w,
    const float* __restrict__ yflip_gate,
    const int*   __restrict__ rot_w,
    const float* __restrict__ rot_gate,
    const float* __restrict__ trans_w,
    const float* __restrict__ trans_gate,
    float* __restrict__ out)
{
    __shared__ __align__(16) float ldsf[32 * LSF];   // 12.8 KB staging
    __shared__ __align__(16) int   syv768[32];       // source row * 768
    __shared__ __align__(16) int   sxr[32];          // within-row source index
    __shared__ __align__(16) int   rc[96];           // read-phase float-col table
    __shared__ int info[2];                          // {fast_flag, sxmin}

    const int n       = blockIdx.x >> 6;
    const int tile_id = blockIdx.x & 63;
    const int yo0     = (tile_id >> 3) << 5;
    const int xo0     = (tile_id & 7) << 5;

    // ---- per-sample parameters (wave-uniform) ----
    const bool xf = (xflip_gate[n] < 1.0f) && (xflip_w[n] == 1);
    const bool yf = (yflip_gate[n] < 1.0f) && (yflip_w[n] == 1);
    const int  rw = (rot_gate[n] < 1.0f) ? rot_w[n] : 0;
    const bool fx = ((rw == 1) || (rw == 2)) ^ xf;
    const bool fy = ((rw == 2) || (rw == 3)) ^ yf;
    const bool tr = (rw == 1) || (rw == 3);

    float tw0 = trans_w[n]      * 2.0f - 1.0f;
    float tw1 = trans_w[NN + n] * 2.0f - 1.0f;
    if (!(trans_gate[n] < 1.0f)) { tw0 = 0.0f; tw1 = 0.0f; }
    const int tx = (int)rintf(tw0 * (WW * 0.125f));
    const int ty = (int)rintf(tw1 * (HH * 0.125f));

    // ---- index tables ----
    // tr=0: out(i,j) = src[sy[i]][sx[j]] ; tr=1: out(i,j) = src[sy[j]][sx[i]]
    {
        const int t = threadIdx.x;
        if (t < 32) {
            int v = tr ? reflect_idx(xo0 + t - tx, WW)
                       : reflect_idx(yo0 + t + ty, HH);
            if (fy) v = HH - 1 - v;
            syv768[t] = v * ROWF;
        } else if (t < 64) {
            const int u = t - 32;
            int v = tr ? reflect_idx(yo0 + u + ty, HH)
                       : reflect_idx(xo0 + u - tx, WW);
            if (fx) v = WW - 1 - v;
            sxr[u] = v;
        }
    }
    __syncthreads();
    if (threadIdx.x == 0) {
        int mn = sxr[0], mx = sxr[0];
        #pragma unroll
        for (int u = 1; u < 32; ++u) {
            const int v = sxr[u];
            mn = min(mn, v); mx = max(mx, v);
        }
        info[0] = (mx - mn == 31);   // contiguous span (no reflection fold)
        info[1] = mn;
    }
    __syncthreads();
    const int fast = info[0];
    const int mn   = info[1];
    const int base_f = mn * 3;
    const int align4 = min(base_f & ~3, ROWF - WIN);  // keep window inside row
    const int shift  = base_f - align4;               // 0..4

    if (threadIdx.x < 96) {
        const int m  = threadIdx.x;
        const int jm = (m * 171) >> 9;    // m/3
        const int cm = m - 3 * jm;
        rc[m] = fast ? ((sxr[jm] - mn) * 3 + cm + shift) : m;
    }
    __syncthreads();

    const float* __restrict__ src = images + (size_t)n * HWC;

    // ---- fill phase ----
    if (fast) {
        // 32 rows x 25 float4, fully coalesced dwordx4 loads
        float4* lds4 = (float4*)ldsf;
        #pragma unroll
        for (int v = 0; v < 4; ++v) {
            const int f = threadIdx.x + v * 256;
            if (f < 800) {
                const int row = (f * 1311) >> 15;   // f/25
                const int q   = f - row * 25;
                const float4* srow = (const float4*)(src + syv768[row] + align4);
                lds4[row * 25 + q] = srow[q];
            }
        }
    } else {
        // folded span: scalar gather fill (rare, ~1/8 of blocks)
        #pragma unroll
        for (int v = 0; v < 12; ++v) {
            const int f   = threadIdx.x + v * 256;   // < 3072
            const int j5  = f >> 5;
            const int row = (j5 * 171) >> 9;         // f/96
            const int m   = f - row * 96;
            const int jm  = (m * 171) >> 9;          // m/3
            const int cm  = m - 3 * jm;
            ldsf[row * LSF + m] = src[syv768[row] + sxr[jm] * 3 + cm];
        }
    }
    __syncthreads();

    // ---- read + store phase: 768 float4 per block ----
    const size_t outBase4 = (size_t)(n * HH + yo0) * (ROWF / 4) + ((xo0 * 3) >> 2);
    float4* __restrict__ out4 = (float4*)out;
    const int4* rc4 = (const int4*)rc;

    #pragma unroll
    for (int v = 0; v < 3; ++v) {
        const int q4 = threadIdx.x + v * 256;        // < 768
        const int i  = (q4 * 683) >> 14;             // q4/24 (output row in tile)
        const int q2 = q4 - i * 24;                  // float4 within row
        float4 o;
        if (!tr) {
            const int4 r = rc4[q2];
            const float* lrow = ldsf + i * LSF;
            o.x = lrow[r.x]; o.y = lrow[r.y]; o.z = lrow[r.z]; o.w = lrow[r.w];
        } else {
            const int rci0 = rc[i * 3 + 0];
            const int rci1 = rc[i * 3 + 1];
            const int rci2 = rc[i * 3 + 2];
            #pragma unroll
            for (int u = 0; u < 4; ++u) {
                const int k2 = 4 * q2 + u;
                const int j  = (k2 * 171) >> 9;      // k2/3
                const int c  = k2 - 3 * j;
                const int rcv = (c == 0) ? rci0 : ((c == 1) ? rci1 : rci2);
                ((float*)&o)[u] = ldsf[j * LSF + rcv];
            }
        }
        out4[outBase4 + (size_t)i * (ROWF / 4) + q2] = o;
    }
}

extern "C" void kernel_launch(void* const* d_in, const int* in_sizes, int n_in,
                              void* d_out, int out_size, void* d_ws, size_t ws_size,
                              hipStream_t stream)
{
    const float* images     = (const float*)d_in[0];
    const int*   xflip_w    = (const int*)  d_in[1];
    const float* xflip_gate = (const float*)d_in[2];
    const int*   yflip_w    = (const int*)  d_in[3];
    const float* yflip_gate = (const float*)d_in[4];
    const int*   rot_w      = (const int*)  d_in[5];
    const float* rot_gate   = (const float*)d_in[6];
    const float* trans_w    = (const float*)d_in[7];   // [2*N] flat
    const float* trans_gate = (const float*)d_in[8];   // [N] flat
    float* outp = (float*)d_out;

    dim3 grid(NN * 64);   // 8x8 tiles of 32x32 pixels per sample
    dim3 block(256);
    augment_kernel<<<grid, block, 0, stream>>>(images, xflip_w, xflip_gate,
                                               yflip_w, yflip_gate, rot_w, rot_gate,
                                               trans_w, trans_gate, outp);
}

// Round 5
// 34.623 us; speedup vs baseline: 1.1358x; 1.1358x over previous
//
#include <hip/hip_runtime.h>

#define NN 128
#define HH 256
#define WW 256
#define CC 3
#define HWC (HH * WW * CC)
#define ROWF (WW * CC)     // 768 floats per image row
#define LSTR 99            // LDS row stride (floats); lane-consecutive reads -> 0 conflicts (R2)

__device__ __forceinline__ int reflect_idx(int v, int size) {
    int period = 2 * size - 2;
    int m = v % period;
    if (m < 0) m += period;
    return size - 1 - abs(size - 1 - m);
}

__global__ __launch_bounds__(256) void augment_kernel(
    const float* __restrict__ images,
    const int*   __restrict__ xflip_w,
    const float* __restrict__ xflip_gate,
    const int*   __restrict__ yflip_w,
    const float* __restrict__ yflip_gate,
    const int*   __restrict__ rot_w,
    const float* __restrict__ rot_gate,
    const float* __restrict__ trans_w,
    const float* __restrict__ trans_gate,
    float* __restrict__ out)
{
    __shared__ __align__(16) int   syv768[32];     // source row * 768
    __shared__ __align__(16) int   sxc[96];        // sx[k/3]*3 + k%3
    __shared__ __align__(16) float tile[32 * LSTR];

    // XCD swizzle: 8192 blocks, 8 XCDs -> each XCD owns 16 whole samples
    // (sample image = 768 KB fits 4 MB XCD L2 -> all 64 tiles L2-hit)
    const int bid     = blockIdx.x;
    const int logical = (bid & 7) * 1024 + (bid >> 3);
    const int n       = logical >> 6;
    const int tile_id = logical & 63;
    const int yo0     = (tile_id >> 3) << 5;
    const int xo0     = (tile_id & 7) << 5;

    // ---- per-sample parameters (wave-uniform) ----
    const bool xf = (xflip_gate[n] < 1.0f) && (xflip_w[n] == 1);
    const bool yf = (yflip_gate[n] < 1.0f) && (yflip_w[n] == 1);
    const int  rw = (rot_gate[n] < 1.0f) ? rot_w[n] : 0;
    const bool fx = ((rw == 1) || (rw == 2)) ^ xf;
    const bool fy = ((rw == 2) || (rw == 3)) ^ yf;
    const bool tr = (rw == 1) || (rw == 3);

    float tw0 = trans_w[n]      * 2.0f - 1.0f;
    float tw1 = trans_w[NN + n] * 2.0f - 1.0f;
    if (!(trans_gate[n] < 1.0f)) { tw0 = 0.0f; tw1 = 0.0f; }
    const int tx = (int)rintf(tw0 * (WW * 0.125f));
    const int ty = (int)rintf(tw1 * (HH * 0.125f));

    // ---- index tables, one sync ----
    // tr=0: out(i,j) = src[sy[i]][sx[j]] ; tr=1: out(i,j) = src[sy[j]][sx[i]]
    {
        const int t = threadIdx.x;
        if (t < 96) {
            const int b = (t * 171) >> 9;      // t/3
            const int c = t - 3 * b;
            int v = tr ? reflect_idx(yo0 + b + ty, HH)
                       : reflect_idx(xo0 + b - tx, WW);
            if (fx) v = WW - 1 - v;
            sxc[t] = v * 3 + c;
        } else if (t < 128) {
            const int a = t - 96;
            int v = tr ? reflect_idx(xo0 + a - tx, WW)
                       : reflect_idx(yo0 + a + ty, HH);
            if (fy) v = HH - 1 - v;
            syv768[a] = v * ROWF;
        }
    }
    __syncthreads();

    const float* __restrict__ src = images + (size_t)n * HWC;

    if (!tr) {
        // ---- direct path (R3): 12 register gathers -> 3 float4 stores, no LDS ----
        const size_t outBase = (size_t)(n * HH + yo0) * ROWF + xo0 * CC; // 384B aligned
        float4* __restrict__ out4 = (float4*)(out + outBase);
        const int4* sxc4 = (const int4*)sxc;

        int   ib[3], qb[3];
        int4  off[3];
        float vals[12];
        #pragma unroll
        for (int v = 0; v < 3; ++v) {
            const int f = v * 256 + threadIdx.x;   // float4 index in [0,768)
            ib[v] = f / 24;
            qb[v] = f - ib[v] * 24;
            off[v] = sxc4[qb[v]];
        }
        #pragma unroll
        for (int v = 0; v < 3; ++v) {
            const int base = syv768[ib[v]];
            vals[v * 4 + 0] = src[base + off[v].x];
            vals[v * 4 + 1] = src[base + off[v].y];
            vals[v * 4 + 2] = src[base + off[v].z];
            vals[v * 4 + 3] = src[base + off[v].w];
        }
        #pragma unroll
        for (int v = 0; v < 3; ++v) {
            out4[ib[v] * (ROWF / 4) + qb[v]] =
                make_float4(vals[v * 4 + 0], vals[v * 4 + 1],
                            vals[v * 4 + 2], vals[v * 4 + 3]);
        }
    } else {
        // ---- transposed path (R2 layout + ILP batching) ----
        // fill: pixel-major; 96-thread groups read one source row's 96-float run
        float vals[12];
        #pragma unroll
        for (int v = 0; v < 12; ++v) {
            const int f  = threadIdx.x + v * 256;  // < 3072
            const int g  = f >> 5;                 // 0..95
            const int j  = (g * 171) >> 9;         // f/96  (source-row group = out col)
            const int m  = f - 96 * j;             // 0..95 -> (i,c)
            vals[v] = src[syv768[j] + sxc[m]];
        }
        #pragma unroll
        for (int v = 0; v < 12; ++v) {
            const int f  = threadIdx.x + v * 256;
            const int g  = f >> 5;
            const int j  = (g * 171) >> 9;
            const int m  = f - 96 * j;
            const int i  = (m * 171) >> 9;         // m/3
            const int c  = m - 3 * i;
            tile[i * LSTR + 3 * j + c] = vals[v];  // banks 3i+3j+c: <=2-way
        }
        __syncthreads();
        // read+store: lane-consecutive floats -> 0 LDS conflicts, coalesced stores
        const size_t outB = (size_t)(n * HH + yo0) * ROWF + xo0 * CC;
        #pragma unroll
        for (int v = 0; v < 12; ++v) {
            const int e = threadIdx.x + v * 256;   // < 3072
            const int g = e >> 5;
            const int i = (g * 171) >> 9;          // e/96 (output row in tile)
            const int k = e - 96 * i;
            out[outB + (size_t)i * ROWF + k] = tile[i * LSTR + k];
        }
    }
}

extern "C" void kernel_launch(void* const* d_in, const int* in_sizes, int n_in,
                              void* d_out, int out_size, void* d_ws, size_t ws_size,
                              hipStream_t stream)
{
    const float* images     = (const float*)d_in[0];
    const int*   xflip_w    = (const int*)  d_in[1];
    const float* xflip_gate = (const float*)d_in[2];
    const int*   yflip_w    = (const int*)  d_in[3];
    const float* yflip_gate = (const float*)d_in[4];
    const int*   rot_w      = (const int*)  d_in[5];
    const float* rot_gate   = (const float*)d_in[6];
    const float* trans_w    = (const float*)d_in[7];   // [2*N] flat
    const float* trans_gate = (const float*)d_in[8];   // [N] flat
    float* outp = (float*)d_out;

    dim3 grid(NN * 64);   // 8x8 tiles of 32x32 pixels per sample
    dim3 block(256);
    augment_kernel<<<grid, block, 0, stream>>>(images, xflip_w, xflip_gate,
                                               yflip_w, yflip_gate, rot_w, rot_gate,
                                               trans_w, trans_gate, outp);
}